// Round 6
// baseline (236.644 us; speedup 1.0000x reference)
//
#include <hip/hip_runtime.h>
#include <hip/hip_bf16.h>

#define N 2048
#define NM1 2047
#define DT 256
#define ET 32
#define EC 128
#define NC 5
#define FS 80    // feats row stride (floats)
#define FD 69    // used feature cols
#define KC_ET 16 // k-chunks for ET GEMMs (chunk = 128)
#define KC_EC 16 // k-chunks for EC GEMM (chunk = 128)

typedef __hip_bfloat16 bf16;

// ---- deg via shifted column sums + label mask (fused) ----
__global__ __launch_bounds__(256) void k_deg_label(const float* __restrict__ tw,
                                                   const float* __restrict__ fw,
                                                   const int* __restrict__ labels,
                                                   float* __restrict__ degT,
                                                   float* __restrict__ degF,
                                                   float* __restrict__ cols){
    int b = blockIdx.x;
    int t = threadIdx.x;
    if (b == 512){
        __shared__ float lc[NC];
        if (t < NC) lc[t] = 0.f;
        __syncthreads();
        for (int i = t; i < N; i += 256){
            int l = labels[i];
            if (l >= 0 && l < NC) lc[l] = 1.f;
        }
        __syncthreads();
        if (t < NC) cols[t] = lc[t];
        return;
    }
    int p = (b & 7)*256 + t;
    if (p >= NM1) return;
    int s0 = (b >> 3)*32;
    float lowT=0.f, highT=0.f, lowF=0.f, highF=0.f;
    #pragma unroll 8
    for (int r = 0; r < 32; ++r){
        int s = s0 + r;
        float vt = tw[(size_t)s*NM1 + p];
        float vf = fw[(size_t)s*NM1 + p];
        if (s <= p){ highT += vt; highF += vf; }
        else       { lowT  += vt; lowF  += vf; }
    }
    atomicAdd(&degT[p],   lowT);
    atomicAdd(&degF[p],   lowF);
    atomicAdd(&degT[p+1], highT);
    atomicAdd(&degF[p+1], highF);
}

// ---- Z[j][f] = rsqrt(1+deg[j]) * (X[j,:] @ W[:,f]), both (t,f) via blockIdx.y ----
__global__ __launch_bounds__(256) void k_xw2(const float* __restrict__ Xt,
                                             const float* __restrict__ Wt,
                                             const float* __restrict__ degT,
                                             float* __restrict__ Zt,
                                             const float* __restrict__ Xf,
                                             const float* __restrict__ Wf,
                                             const float* __restrict__ degF,
                                             float* __restrict__ Zf){
    const float* X   = blockIdx.y ? Xf   : Xt;
    const float* W   = blockIdx.y ? Wf   : Wt;
    const float* deg = blockIdx.y ? degF : degT;
    float*       Z   = blockIdx.y ? Zf   : Zt;
    __shared__ float Ws[DT*ET];
    __shared__ float Xs[8*DT];
    int t = threadIdx.x;
    for (int idx = t; idx < DT*ET; idx += 256) Ws[idx] = W[idx];
    int i0 = blockIdx.x*8;
    for (int idx = t; idx < 8*DT; idx += 256) Xs[idx] = X[(size_t)i0*DT + idx];
    __syncthreads();
    int r = t >> 5, f = t & 31;
    const float* xr = Xs + r*DT;
    float acc = 0.f;
    #pragma unroll 8
    for (int d = 0; d < DT; ++d) acc += xr[d]*Ws[d*ET+f];
    int i = i0 + r;
    Z[(size_t)i*ET+f] = rsqrtf(1.f + deg[i])*acc;
}

// ---- split-K GEMM (both graphs): P[kc][i][f] = sum_{k in chunk,k!=i} A[i,k]*Z[k][f]
// A[i,k] = tw[k*2047 + i - (i>k)].  128 threads, 64x32 tile, 4x4 micro, all-b128.
__global__ __launch_bounds__(128) void k_agg_et(const float* __restrict__ tw,
                                                const float* __restrict__ fw,
                                                const float* __restrict__ Zt,
                                                const float* __restrict__ Zf,
                                                float* __restrict__ Pt,
                                                float* __restrict__ Pf){
    __shared__ float Ast[64*68];   // [k][i]
    __shared__ float Asf[64*68];
    __shared__ float Zst[64*ET];   // [k][f]
    __shared__ float Zsf[64*ET];
    int t = threadIdx.x;
    int i0 = blockIdx.x*64;
    int kc = blockIdx.y;           // 0..15, chunk 128
    int k0 = kc*128;
    int rowg = t >> 3;             // 0..15
    int colth = t & 7;             // 0..7
    int r0 = rowg*4, c0 = colth*4;
    float accT[4][4], accF[4][4];
    #pragma unroll
    for (int u=0;u<4;++u)
        #pragma unroll
        for (int v=0;v<4;++v){ accT[u][v]=0.f; accF[u][v]=0.f; }

    for (int kt = 0; kt < 2; ++kt){
        int kb = k0 + kt*64;
        // stage A (k-major), diag=0
        #pragma unroll
        for (int e = 0; e < 32; ++e){
            int id = t + e*128;            // 0..4095
            int k_l = id >> 6, i_l = id & 63;
            int k = kb + k_l;
            int gi = i0 + i_l;
            float vt, vf;
            if (gi == k){ vt = 0.f; vf = 0.f; }
            else {
                size_t base = (size_t)k*NM1 + gi - (gi > k ? 1 : 0);
                vt = tw[base]; vf = fw[base];
            }
            Ast[k_l*68 + i_l] = vt;
            Asf[k_l*68 + i_l] = vf;
        }
        // stage Z
        #pragma unroll
        for (int e = 0; e < 4; ++e){
            int id = t + e*128;            // 0..511 float4 ids over 64x32
            int row = id >> 3;
            int c4  = (id & 7)*4;
            *(float4*)&Zst[row*ET + c4] = *(const float4*)&Zt[(size_t)(kb+row)*ET + c4];
            *(float4*)&Zsf[row*ET + c4] = *(const float4*)&Zf[(size_t)(kb+row)*ET + c4];
        }
        __syncthreads();
        for (int k = 0; k < 64; ++k){
            float4 at = *(const float4*)&Ast[k*68 + r0];
            float4 af = *(const float4*)&Asf[k*68 + r0];
            float4 zt = *(const float4*)&Zst[k*ET + c0];
            float4 zf = *(const float4*)&Zsf[k*ET + c0];
            const float* ap = (const float*)&at;
            const float* bp = (const float*)&af;
            const float* zp = (const float*)&zt;
            const float* wp = (const float*)&zf;
            #pragma unroll
            for (int u = 0; u < 4; ++u)
                #pragma unroll
                for (int v = 0; v < 4; ++v){
                    accT[u][v] += ap[u]*zp[v];
                    accF[u][v] += bp[u]*wp[v];
                }
        }
        __syncthreads();
    }
    #pragma unroll
    for (int u = 0; u < 4; ++u){
        size_t ii = (size_t)(i0 + r0 + u);
        float4 ot, of;
        float* pt = (float*)&ot; float* pf = (float*)&of;
        #pragma unroll
        for (int v = 0; v < 4; ++v){ pt[v]=accT[u][v]; pf[v]=accF[u][v]; }
        *(float4*)&Pt[(size_t)kc*(N*ET) + ii*ET + c0] = ot;
        *(float4*)&Pf[(size_t)kc*(N*ET) + ii*ET + c0] = of;
    }
}

// ---- reduce partials + self term + dis*(.)+bias + lrelu + onehot -> feats ----
__global__ __launch_bounds__(256) void k_feats_epi(const float* __restrict__ Pt,
                                                   const float* __restrict__ Pf,
                                                   const float* __restrict__ Zt,
                                                   const float* __restrict__ Zf,
                                                   const float* __restrict__ degT,
                                                   const float* __restrict__ degF,
                                                   const float* __restrict__ bt,
                                                   const float* __restrict__ bfv,
                                                   const float* __restrict__ cols,
                                                   const int* __restrict__ qsize,
                                                   float* __restrict__ feats){
    int idx = blockIdx.x*256 + threadIdx.x;   // over 2048*64
    int i = idx >> 6;
    int f = idx & 63;
    float s, rd, b;
    if (f < ET){
        s = Zt[(size_t)i*ET + f];
        #pragma unroll
        for (int kc = 0; kc < KC_ET; ++kc) s += Pt[(size_t)kc*(N*ET) + (size_t)i*ET + f];
        rd = rsqrtf(1.f + degT[i]);
        b = bt[f];
    } else {
        int g = f - ET;
        s = Zf[(size_t)i*ET + g];
        #pragma unroll
        for (int kc = 0; kc < KC_ET; ++kc) s += Pf[(size_t)kc*(N*ET) + (size_t)i*ET + g];
        rd = rsqrtf(1.f + degF[i]);
        b = bfv[g];
    }
    float v = rd*s + b;
    feats[(size_t)i*FS + f] = v > 0.f ? v : 0.01f*v;
    if (f < NC){
        int nsup = N - qsize[0];
        feats[(size_t)i*FS + 2*ET + f] = (i < nsup) ? cols[f] : 0.f;
    }
}

// ---- Aw[i][j] = (i==j) ? 1 : 1/(L1+1e-5); fused row-sum atomics into dsum ----
__global__ __launch_bounds__(256) void k_build_aw(const float* __restrict__ feats,
                                                  float* __restrict__ Aw,
                                                  float* __restrict__ dsum){
    __shared__ float fiT[64*68];   // [dim][row]
    __shared__ float fjT[64*68];
    int t = threadIdx.x;
    int i0 = blockIdx.x*64, j0 = blockIdx.y*64;
    {
        int row = t >> 2;
        int cb  = (t & 3)*16;
        const float4* si = (const float4*)(feats + (size_t)(i0+row)*FS + cb);
        const float4* sj = (const float4*)(feats + (size_t)(j0+row)*FS + cb);
        #pragma unroll
        for (int s = 0; s < 4; ++s){
            float4 v = si[s];
            float4 w = sj[s];
            int c = cb + s*4;
            fiT[(c+0)*68+row]=v.x; fiT[(c+1)*68+row]=v.y; fiT[(c+2)*68+row]=v.z; fiT[(c+3)*68+row]=v.w;
            fjT[(c+0)*68+row]=w.x; fjT[(c+1)*68+row]=w.y; fjT[(c+2)*68+row]=w.z; fjT[(c+3)*68+row]=w.w;
        }
    }
    __syncthreads();
    int tx = t & 15, ty = t >> 4;
    float acc[4][4];
    #pragma unroll
    for (int u=0;u<4;++u)
        #pragma unroll
        for (int v=0;v<4;++v) acc[u][v]=0.f;
    for (int d = 0; d < 64; ++d){
        float4 a4 = *(const float4*)&fiT[d*68 + ty*4];
        float4 b4 = *(const float4*)&fjT[d*68 + tx*4];
        const float* ap = (const float*)&a4;
        const float* bp = (const float*)&b4;
        #pragma unroll
        for (int u = 0; u < 4; ++u)
            #pragma unroll
            for (int v = 0; v < 4; ++v)
                acc[u][v] += fabsf(ap[u]-bp[v]);
    }
    #pragma unroll
    for (int u = 0; u < 4; ++u){
        int gi = i0 + ty*4 + u;
        float4 o;
        float* po = (float*)&o;
        #pragma unroll
        for (int v = 0; v < 4; ++v){
            int gj = j0 + tx*4 + v;
            po[v] = (gi==gj) ? 1.0f : 1.0f/(acc[u][v] + 1e-5f);
        }
        *(float4*)&Aw[(size_t)gi*N + j0 + tx*4] = o;
        float rs = (po[0]+po[1]) + (po[2]+po[3]);
        rs += __shfl_xor(rs, 1);
        rs += __shfl_xor(rs, 2);
        rs += __shfl_xor(rs, 4);
        rs += __shfl_xor(rs, 8);
        if (tx == 0) atomicAdd(&dsum[gi], rs);
    }
}

// ---- Zc[i][f] = rsqrt(dsum[i]) * (feats[i,0:69] @ Wc[:,f]) ----
__global__ __launch_bounds__(256) void k_featswc(const float* __restrict__ feats,
                                                 const float* __restrict__ Wc,
                                                 const float* __restrict__ dsum,
                                                 float* __restrict__ Zc){
    __shared__ float Wcs[FD*EC];
    __shared__ float fr[8][FD+3];
    int t = threadIdx.x; // 256
    for (int idx = t; idx < FD*EC; idx += 256) Wcs[idx] = Wc[idx];
    int i0 = blockIdx.x*8;
    for (int idx = t; idx < 8*FD; idx += 256){
        int r = idx / FD;
        int c = idx - r*FD;
        fr[r][c] = feats[(size_t)(i0+r)*FS + c];
    }
    __syncthreads();
    int f  = t & 127;
    int rh = t >> 7;
    for (int rr = 0; rr < 4; ++rr){
        int r = rh*4 + rr;
        float acc = 0.f;
        #pragma unroll
        for (int d = 0; d < FD; ++d) acc += fr[r][d]*Wcs[d*EC+f];
        int i = i0 + r;
        Zc[(size_t)i*EC + f] = rsqrtf(dsum[i])*acc;
    }
}

// ---- split-K GEMM: Pe[kc][i][f] = sum_{k in chunk} Aw[i,k]*Zc[k][f]
// 128 threads, 64x128 tile, 8x8 micro, k-major A in LDS, all-b128 reads.
__global__ __launch_bounds__(128) void k_agg_ec(const float* __restrict__ Aw,
                                                const float* __restrict__ Zc,
                                                float* __restrict__ Pe){
    __shared__ float AwT[64*68];    // [k][i]
    __shared__ float Zs[64*132];    // [k][f] padded
    int t = threadIdx.x;
    int i0 = blockIdx.x*64;
    int kc = blockIdx.y;            // 0..15, chunk 128
    int k0 = kc*128;
    int colth = t & 15, rowg = t >> 4;  // 16 x 8
    int r0 = rowg*8, c0 = colth*8;
    float acc[8][8];
    #pragma unroll
    for (int u=0;u<8;++u)
        #pragma unroll
        for (int v=0;v<8;++v) acc[u][v]=0.f;

    for (int kt = 0; kt < 2; ++kt){
        int kb = k0 + kt*64;
        // stage A transposed: read Aw rows (k contiguous), write [k][i]
        #pragma unroll
        for (int e = 0; e < 8; ++e){
            int id = t + e*128;          // 0..1023 float4 ids over 64i x 16k4
            int i_l = id >> 4;
            int k4  = (id & 15)*4;
            float4 v = *(const float4*)&Aw[(size_t)(i0+i_l)*N + kb + k4];
            AwT[(k4+0)*68 + i_l] = v.x;
            AwT[(k4+1)*68 + i_l] = v.y;
            AwT[(k4+2)*68 + i_l] = v.z;
            AwT[(k4+3)*68 + i_l] = v.w;
        }
        // stage Z
        #pragma unroll
        for (int e = 0; e < 16; ++e){
            int id = t + e*128;          // 0..2047 float4 ids over 64x128
            int row = id >> 5;
            int c4  = (id & 31)*4;
            *(float4*)&Zs[row*132 + c4] = *(const float4*)&Zc[(size_t)(kb+row)*EC + c4];
        }
        __syncthreads();
        for (int k = 0; k < 64; ++k){
            float4 alo = *(const float4*)&AwT[k*68 + r0];
            float4 ahi = *(const float4*)&AwT[k*68 + r0 + 4];
            float4 zlo = *(const float4*)&Zs[k*132 + c0];
            float4 zhi = *(const float4*)&Zs[k*132 + c0 + 4];
            float a8[8] = {alo.x,alo.y,alo.z,alo.w,ahi.x,ahi.y,ahi.z,ahi.w};
            float z8[8] = {zlo.x,zlo.y,zlo.z,zlo.w,zhi.x,zhi.y,zhi.z,zhi.w};
            #pragma unroll
            for (int u = 0; u < 8; ++u)
                #pragma unroll
                for (int v = 0; v < 8; ++v)
                    acc[u][v] += a8[u]*z8[v];
        }
        __syncthreads();
    }
    #pragma unroll
    for (int u = 0; u < 8; ++u){
        size_t ii = (size_t)(i0 + r0 + u);
        float4 o0, o1;
        float* p0 = (float*)&o0; float* p1 = (float*)&o1;
        #pragma unroll
        for (int v = 0; v < 4; ++v){ p0[v]=acc[u][v]; p1[v]=acc[u][v+4]; }
        *(float4*)&Pe[(size_t)kc*(N*EC) + ii*EC + c0]     = o0;
        *(float4*)&Pe[(size_t)kc*(N*EC) + ii*EC + c0 + 4] = o1;
    }
}

// ---- reduce Pe + rsqrt(dsum)*(.)+bc + lrelu -> emb ----
__global__ __launch_bounds__(256) void k_emb_epi(const float* __restrict__ Pe,
                                                 const float* __restrict__ dsum,
                                                 const float* __restrict__ bc,
                                                 float* __restrict__ emb){
    int idx = blockIdx.x*256 + threadIdx.x;   // over 2048*128
    int i = idx >> 7, f = idx & 127;
    float s = 0.f;
    #pragma unroll
    for (int kc = 0; kc < KC_EC; ++kc) s += Pe[(size_t)kc*(N*EC) + (size_t)idx];
    float v = rsqrtf(dsum[i])*s + bc[f];
    emb[idx] = v > 0.f ? v : 0.01f*v;
}

// ---- out[i][c] = emb[i,:] @ Wo[:,c] + bo[c] ----
__global__ __launch_bounds__(256) void k_final(const float* __restrict__ emb,
                                               const float* __restrict__ Wo,
                                               const float* __restrict__ bo,
                                               float* __restrict__ out){
    __shared__ float Wos[EC*NC];
    __shared__ float bos[NC];
    int t = threadIdx.x;
    for (int idx = t; idx < EC*NC; idx += 256) Wos[idx] = Wo[idx];
    if (t < NC) bos[t] = bo[t];
    __syncthreads();
    int idx = blockIdx.x*256 + t;   // N*NC/256 = 40 blocks
    int i = idx / NC;
    int c = idx - i*NC;
    float acc = bos[c];
    const float* er = emb + (size_t)i*EC;
    #pragma unroll 8
    for (int f = 0; f < EC; ++f) acc += er[f]*Wos[f*NC+c];
    out[idx] = acc;
}

extern "C" void kernel_launch(void* const* d_in, const int* in_sizes, int n_in,
                              void* d_out, int out_size, void* d_ws, size_t ws_size,
                              hipStream_t stream) {
    const float* time_features = (const float*)d_in[0];
    const float* tw            = (const float*)d_in[2];
    const float* freq_features = (const float*)d_in[3];
    const float* fw            = (const float*)d_in[4];
    const int*   labels        = (const int*)d_in[5];
    const int*   qsize         = (const int*)d_in[7];
    const float* Wt  = (const float*)d_in[8];
    const float* bt  = (const float*)d_in[9];
    const float* Wf  = (const float*)d_in[10];
    const float* bfv = (const float*)d_in[11];
    const float* Wc  = (const float*)d_in[12];
    const float* bc  = (const float*)d_in[13];
    const float* Wo  = (const float*)d_in[14];
    const float* bo  = (const float*)d_in[15];
    float* out = (float*)d_out;

    float* ws    = (float*)d_ws;
    float* Zt    = ws;                         // N*ET
    float* Zf    = Zt + (size_t)N*ET;          // N*ET
    float* Zc    = Zf + (size_t)N*ET;          // N*EC
    float* degT  = Zc + (size_t)N*EC;          // N   (zeroed)
    float* degF  = degT + N;                   // N   (zeroed)
    float* dsum  = degF + N;                   // N   (zeroed)
    float* colsb = dsum + N;                   // 8
    float* feats = colsb + 8;                  // N*FS
    float* emb   = feats + (size_t)N*FS;       // N*EC
    float* Aw    = emb + (size_t)N*EC;         // N*N
    float* Pt    = Aw + (size_t)N*N;           // KC_ET*N*ET
    float* Pf    = Pt + (size_t)KC_ET*N*ET;    // KC_ET*N*ET
    float* Pe    = Pf + (size_t)KC_ET*N*ET;    // KC_EC*N*EC

    hipMemsetAsync(degT, 0, 3*N*sizeof(float), stream);
    k_deg_label<<<513, 256, 0, stream>>>(tw, fw, labels, degT, degF, colsb);
    k_xw2<<<dim3(N/8, 2), 256, 0, stream>>>(time_features, Wt, degT, Zt,
                                            freq_features, Wf, degF, Zf);
    k_agg_et<<<dim3(N/64, KC_ET), 128, 0, stream>>>(tw, fw, Zt, Zf, Pt, Pf);
    k_feats_epi<<<(N*64)/256, 256, 0, stream>>>(Pt, Pf, Zt, Zf, degT, degF,
                                                bt, bfv, colsb, qsize, feats);
    k_build_aw<<<dim3(N/64, N/64), 256, 0, stream>>>(feats, Aw, dsum);
    k_featswc<<<N/8, 256, 0, stream>>>(feats, Wc, dsum, Zc);
    k_agg_ec<<<dim3(N/64, KC_EC), 128, 0, stream>>>(Aw, Zc, Pe);
    k_emb_epi<<<(N*EC)/256, 256, 0, stream>>>(Pe, dsum, bc, emb);
    k_final<<<(N*NC)/256, 256, 0, stream>>>(emb, Wo, bo, out);
}

// Round 7
// 212.081 us; speedup vs baseline: 1.1158x; 1.1158x over previous
//
#include <hip/hip_runtime.h>
#include <hip/hip_bf16.h>

#define N 2048
#define NM1 2047
#define DT 256
#define ET 32
#define EC 128
#define NC 5
#define FS 80    // feats row stride (floats)
#define FD 69    // used feature cols
#define KC_ET 16 // k-chunks for ET GEMMs (chunk = 128)
#define KC_EC 16 // k-chunks for EC GEMM (chunk = 128)

typedef __hip_bfloat16 bf16;

// ---- deg via shifted column sums + label mask (fused) ----
__global__ __launch_bounds__(256) void k_deg_label(const float* __restrict__ tw,
                                                   const float* __restrict__ fw,
                                                   const int* __restrict__ labels,
                                                   float* __restrict__ degT,
                                                   float* __restrict__ degF,
                                                   float* __restrict__ cols){
    int b = blockIdx.x;
    int t = threadIdx.x;
    if (b == 512){
        __shared__ float lc[NC];
        if (t < NC) lc[t] = 0.f;
        __syncthreads();
        for (int i = t; i < N; i += 256){
            int l = labels[i];
            if (l >= 0 && l < NC) lc[l] = 1.f;
        }
        __syncthreads();
        if (t < NC) cols[t] = lc[t];
        return;
    }
    int p = (b & 7)*256 + t;
    if (p >= NM1) return;
    int s0 = (b >> 3)*32;
    float lowT=0.f, highT=0.f, lowF=0.f, highF=0.f;
    #pragma unroll 8
    for (int r = 0; r < 32; ++r){
        int s = s0 + r;
        float vt = tw[(size_t)s*NM1 + p];
        float vf = fw[(size_t)s*NM1 + p];
        if (s <= p){ highT += vt; highF += vf; }
        else       { lowT  += vt; lowF  += vf; }
    }
    atomicAdd(&degT[p],   lowT);
    atomicAdd(&degF[p],   lowF);
    atomicAdd(&degT[p+1], highT);
    atomicAdd(&degF[p+1], highF);
}

// ---- Z[j][f] = rsqrt(1+deg[j]) * (X[j,:] @ W[:,f]), both graphs via blockIdx.y ----
__global__ __launch_bounds__(256) void k_xw2(const float* __restrict__ Xt,
                                             const float* __restrict__ Wt,
                                             const float* __restrict__ degT,
                                             float* __restrict__ Zt,
                                             const float* __restrict__ Xf,
                                             const float* __restrict__ Wf,
                                             const float* __restrict__ degF,
                                             float* __restrict__ Zf){
    const float* X   = blockIdx.y ? Xf   : Xt;
    const float* W   = blockIdx.y ? Wf   : Wt;
    const float* deg = blockIdx.y ? degF : degT;
    float*       Z   = blockIdx.y ? Zf   : Zt;
    __shared__ float Ws[DT*ET];
    __shared__ float Xs[8*DT];
    int t = threadIdx.x;
    for (int idx = t; idx < DT*ET; idx += 256) Ws[idx] = W[idx];
    int i0 = blockIdx.x*8;
    for (int idx = t; idx < 8*DT; idx += 256) Xs[idx] = X[(size_t)i0*DT + idx];
    __syncthreads();
    int r = t >> 5, f = t & 31;
    const float* xr = Xs + r*DT;
    float acc = 0.f;
    #pragma unroll 8
    for (int d = 0; d < DT; ++d) acc += xr[d]*Ws[d*ET+f];
    int i = i0 + r;
    Z[(size_t)i*ET+f] = rsqrtf(1.f + deg[i])*acc;
}

// ---- split-K GEMM, both graphs in one block (wave-uniform split) ----
// P[kc][i][f] = sum_{k in chunk,k!=i} A[i,k]*Z[k][f], A[i,k]=tw[k*2047+i-(i>k)]
// 256 thr: threads 0-127 graph T, 128-255 graph F; 4x4 micro, all-b128.
__global__ __launch_bounds__(256) void k_agg_et(const float* __restrict__ tw,
                                                const float* __restrict__ fw,
                                                const float* __restrict__ Zt,
                                                const float* __restrict__ Zf,
                                                float* __restrict__ Pt,
                                                float* __restrict__ Pf){
    __shared__ float Ast[64*68];   // [k][i]
    __shared__ float Asf[64*68];
    __shared__ float Zst[64*ET];   // [k][f]
    __shared__ float Zsf[64*ET];
    int t = threadIdx.x;
    int i0 = blockIdx.x*64;
    int kc = blockIdx.y;           // 0..15, chunk 128
    int k0 = kc*128;
    int g  = t >> 7;               // wave-uniform graph select
    int tt = t & 127;
    int ig = tt >> 3, fg = tt & 7;
    int r0 = ig*4, c0 = fg*4;
    const float* As = g ? Asf : Ast;
    const float* Zs = g ? Zsf : Zst;
    float acc[4][4];
    #pragma unroll
    for (int u=0;u<4;++u)
        #pragma unroll
        for (int v=0;v<4;++v) acc[u][v]=0.f;

    for (int kt = 0; kt < 2; ++kt){
        int kb = k0 + kt*64;
        // stage A (k-major), diag=0; all 256 threads, both matrices
        #pragma unroll
        for (int e = 0; e < 16; ++e){
            int id = t + e*256;            // 0..4095
            int k_l = id >> 6, i_l = id & 63;
            int k = kb + k_l;
            int gi = i0 + i_l;
            float vt, vf;
            if (gi == k){ vt = 0.f; vf = 0.f; }
            else {
                size_t base = (size_t)k*NM1 + gi - (gi > k ? 1 : 0);
                vt = tw[base]; vf = fw[base];
            }
            Ast[k_l*68 + i_l] = vt;
            Asf[k_l*68 + i_l] = vf;
        }
        #pragma unroll
        for (int e = 0; e < 2; ++e){
            int id = t + e*256;            // 0..511 float4 ids over 64x32
            int row = id >> 3;
            int c4  = (id & 7)*4;
            *(float4*)&Zst[row*ET + c4] = *(const float4*)&Zt[(size_t)(kb+row)*ET + c4];
            *(float4*)&Zsf[row*ET + c4] = *(const float4*)&Zf[(size_t)(kb+row)*ET + c4];
        }
        __syncthreads();
        for (int k = 0; k < 64; ++k){
            float4 a = *(const float4*)&As[k*68 + r0];
            float4 z = *(const float4*)&Zs[k*ET + c0];
            const float* ap = (const float*)&a;
            const float* zp = (const float*)&z;
            #pragma unroll
            for (int u = 0; u < 4; ++u)
                #pragma unroll
                for (int v = 0; v < 4; ++v)
                    acc[u][v] += ap[u]*zp[v];
        }
        __syncthreads();
    }
    float* P = g ? Pf : Pt;
    #pragma unroll
    for (int u = 0; u < 4; ++u){
        size_t ii = (size_t)(i0 + r0 + u);
        float4 o;
        float* po = (float*)&o;
        #pragma unroll
        for (int v = 0; v < 4; ++v) po[v]=acc[u][v];
        *(float4*)&P[(size_t)kc*(N*ET) + ii*ET + c0] = o;
    }
}

// ---- reduce partials + self term + dis*(.)+bias + lrelu + onehot -> feats ----
__global__ __launch_bounds__(256) void k_feats_epi(const float* __restrict__ Pt,
                                                   const float* __restrict__ Pf,
                                                   const float* __restrict__ Zt,
                                                   const float* __restrict__ Zf,
                                                   const float* __restrict__ degT,
                                                   const float* __restrict__ degF,
                                                   const float* __restrict__ bt,
                                                   const float* __restrict__ bfv,
                                                   const float* __restrict__ cols,
                                                   const int* __restrict__ qsize,
                                                   float* __restrict__ feats){
    int idx = blockIdx.x*256 + threadIdx.x;   // over 2048*64
    int i = idx >> 6;
    int f = idx & 63;
    float s, rd, b;
    if (f < ET){
        s = Zt[(size_t)i*ET + f];
        #pragma unroll
        for (int kc = 0; kc < KC_ET; ++kc) s += Pt[(size_t)kc*(N*ET) + (size_t)i*ET + f];
        rd = rsqrtf(1.f + degT[i]);
        b = bt[f];
    } else {
        int g = f - ET;
        s = Zf[(size_t)i*ET + g];
        #pragma unroll
        for (int kc = 0; kc < KC_ET; ++kc) s += Pf[(size_t)kc*(N*ET) + (size_t)i*ET + g];
        rd = rsqrtf(1.f + degF[i]);
        b = bfv[g];
    }
    float v = rd*s + b;
    feats[(size_t)i*FS + f] = v > 0.f ? v : 0.01f*v;
    if (f < NC){
        int nsup = N - qsize[0];
        feats[(size_t)i*FS + 2*ET + f] = (i < nsup) ? cols[f] : 0.f;
    }
}

// ---- Aw[i][j] = (i==j) ? 1 : 1/(L1+1e-5); fused row-sum atomics into dsum ----
__global__ __launch_bounds__(256) void k_build_aw(const float* __restrict__ feats,
                                                  float* __restrict__ Aw,
                                                  float* __restrict__ dsum){
    __shared__ float fiT[64*68];   // [dim][row]
    __shared__ float fjT[64*68];
    int t = threadIdx.x;
    int i0 = blockIdx.x*64, j0 = blockIdx.y*64;
    {
        int row = t >> 2;
        int cb  = (t & 3)*16;
        const float4* si = (const float4*)(feats + (size_t)(i0+row)*FS + cb);
        const float4* sj = (const float4*)(feats + (size_t)(j0+row)*FS + cb);
        #pragma unroll
        for (int s = 0; s < 4; ++s){
            float4 v = si[s];
            float4 w = sj[s];
            int c = cb + s*4;
            fiT[(c+0)*68+row]=v.x; fiT[(c+1)*68+row]=v.y; fiT[(c+2)*68+row]=v.z; fiT[(c+3)*68+row]=v.w;
            fjT[(c+0)*68+row]=w.x; fjT[(c+1)*68+row]=w.y; fjT[(c+2)*68+row]=w.z; fjT[(c+3)*68+row]=w.w;
        }
    }
    __syncthreads();
    int tx = t & 15, ty = t >> 4;
    float acc[4][4];
    #pragma unroll
    for (int u=0;u<4;++u)
        #pragma unroll
        for (int v=0;v<4;++v) acc[u][v]=0.f;
    for (int d = 0; d < 64; ++d){
        float4 a4 = *(const float4*)&fiT[d*68 + ty*4];
        float4 b4 = *(const float4*)&fjT[d*68 + tx*4];
        const float* ap = (const float*)&a4;
        const float* bp = (const float*)&b4;
        #pragma unroll
        for (int u = 0; u < 4; ++u)
            #pragma unroll
            for (int v = 0; v < 4; ++v)
                acc[u][v] += fabsf(ap[u]-bp[v]);
    }
    #pragma unroll
    for (int u = 0; u < 4; ++u){
        int gi = i0 + ty*4 + u;
        float4 o;
        float* po = (float*)&o;
        #pragma unroll
        for (int v = 0; v < 4; ++v){
            int gj = j0 + tx*4 + v;
            po[v] = (gi==gj) ? 1.0f : 1.0f/(acc[u][v] + 1e-5f);
        }
        *(float4*)&Aw[(size_t)gi*N + j0 + tx*4] = o;
        float rs = (po[0]+po[1]) + (po[2]+po[3]);
        rs += __shfl_xor(rs, 1);
        rs += __shfl_xor(rs, 2);
        rs += __shfl_xor(rs, 4);
        rs += __shfl_xor(rs, 8);
        if (tx == 0) atomicAdd(&dsum[gi], rs);
    }
}

// ---- Zc[i][f] = rsqrt(dsum[i]) * (feats[i,0:69] @ Wc[:,f]) ----
__global__ __launch_bounds__(256) void k_featswc(const float* __restrict__ feats,
                                                 const float* __restrict__ Wc,
                                                 const float* __restrict__ dsum,
                                                 float* __restrict__ Zc){
    __shared__ float Wcs[FD*EC];
    __shared__ float fr[8][FD+3];
    int t = threadIdx.x; // 256
    for (int idx = t; idx < FD*EC; idx += 256) Wcs[idx] = Wc[idx];
    int i0 = blockIdx.x*8;
    for (int idx = t; idx < 8*FD; idx += 256){
        int r = idx / FD;
        int c = idx - r*FD;
        fr[r][c] = feats[(size_t)(i0+r)*FS + c];
    }
    __syncthreads();
    int f  = t & 127;
    int rh = t >> 7;
    for (int rr = 0; rr < 4; ++rr){
        int r = rh*4 + rr;
        float acc = 0.f;
        #pragma unroll
        for (int d = 0; d < FD; ++d) acc += fr[r][d]*Wcs[d*EC+f];
        int i = i0 + r;
        Zc[(size_t)i*EC + f] = rsqrtf(dsum[i])*acc;
    }
}

// ---- split-K GEMM: Pe[kc][i][f] = sum_{k in chunk} Aw[i,k]*Zc[k][f]
// 256 thr, 128x128 tile, 8x8 micro (split cols), A staged via Aw SYMMETRY
// (Aw[i,k]==Aw[k,i]) -> k-major tile read row-wise, no LDS transpose.
__global__ __launch_bounds__(256) void k_agg_ec(const float* __restrict__ Aw,
                                                const float* __restrict__ Zc,
                                                float* __restrict__ Pe){
    __shared__ float As[64*128];    // [k][i]
    __shared__ float Zs[64*128];    // [k][f]
    int t = threadIdx.x;
    int i0 = blockIdx.x*128;
    int kc = blockIdx.y;            // 0..15, chunk 128
    int k0 = kc*128;
    int rg = t >> 4;                // 0..15 -> rows r0..r0+7
    int cg = t & 15;                // 0..15 -> cols cg*4 and 64+cg*4
    int r0 = rg*8;
    int ca = cg*4, cb = 64 + cg*4;
    float acc[8][8];
    #pragma unroll
    for (int u=0;u<8;++u)
        #pragma unroll
        for (int v=0;v<8;++v) acc[u][v]=0.f;

    for (int kt = 0; kt < 2; ++kt){
        int kb = k0 + kt*64;
        // stage A via symmetry: As[k][i] = Aw[kb+k][i0+i] (coalesced, conflict-free)
        #pragma unroll
        for (int e = 0; e < 8; ++e){
            int id = t + e*256;          // 0..2047 float4 ids over 64k x 32(i4)
            int k_l = id >> 5;
            int i4  = (id & 31)*4;
            *(float4*)&As[k_l*128 + i4] = *(const float4*)&Aw[(size_t)(kb+k_l)*N + i0 + i4];
        }
        // stage Z
        #pragma unroll
        for (int e = 0; e < 8; ++e){
            int id = t + e*256;          // 0..2047 float4 ids over 64x128
            int row = id >> 5;
            int c4  = (id & 31)*4;
            *(float4*)&Zs[row*128 + c4] = *(const float4*)&Zc[(size_t)(kb+row)*EC + c4];
        }
        __syncthreads();
        for (int k = 0; k < 64; ++k){
            float4 a0 = *(const float4*)&As[k*128 + r0];
            float4 a1 = *(const float4*)&As[k*128 + r0 + 4];
            float4 z0 = *(const float4*)&Zs[k*128 + ca];
            float4 z1 = *(const float4*)&Zs[k*128 + cb];
            float a8[8] = {a0.x,a0.y,a0.z,a0.w,a1.x,a1.y,a1.z,a1.w};
            float zl[4] = {z0.x,z0.y,z0.z,z0.w};
            float zh[4] = {z1.x,z1.y,z1.z,z1.w};
            #pragma unroll
            for (int u = 0; u < 8; ++u){
                #pragma unroll
                for (int v = 0; v < 4; ++v){
                    acc[u][v]   += a8[u]*zl[v];
                    acc[u][v+4] += a8[u]*zh[v];
                }
            }
        }
        __syncthreads();
    }
    #pragma unroll
    for (int u = 0; u < 8; ++u){
        size_t ii = (size_t)(i0 + r0 + u);
        float4 o0, o1;
        float* p0 = (float*)&o0; float* p1 = (float*)&o1;
        #pragma unroll
        for (int v = 0; v < 4; ++v){ p0[v]=acc[u][v]; p1[v]=acc[u][v+4]; }
        *(float4*)&Pe[(size_t)kc*(N*EC) + ii*EC + ca] = o0;
        *(float4*)&Pe[(size_t)kc*(N*EC) + ii*EC + cb] = o1;
    }
}

// ---- fused: reduce Pe + rsqrt(dsum)*(.)+bc + lrelu -> emb (LDS) -> out ----
__global__ __launch_bounds__(256) void k_embfinal(const float* __restrict__ Pe,
                                                  const float* __restrict__ dsum,
                                                  const float* __restrict__ bc,
                                                  const float* __restrict__ Wo,
                                                  const float* __restrict__ bo,
                                                  float* __restrict__ out){
    __shared__ float vs[2][EC];
    __shared__ float Wos[EC*NC];
    __shared__ float bos[NC];
    int t = threadIdx.x;
    for (int idx = t; idx < EC*NC; idx += 256) Wos[idx] = Wo[idx];
    if (t < NC) bos[t] = bo[t];
    int rr = t >> 7, f = t & 127;
    int i = blockIdx.x*2 + rr;
    size_t idx = (size_t)i*EC + f;
    float s = 0.f;
    #pragma unroll
    for (int kc = 0; kc < KC_EC; ++kc) s += Pe[(size_t)kc*(N*EC) + idx];
    float v = rsqrtf(dsum[i])*s + bc[f];
    vs[rr][f] = v > 0.f ? v : 0.01f*v;
    __syncthreads();
    if (t < 2*NC){
        int r = t / NC;
        int c = t - r*NC;
        float a = bos[c];
        #pragma unroll 8
        for (int f2 = 0; f2 < EC; ++f2) a += vs[r][f2]*Wos[f2*NC+c];
        out[(size_t)(blockIdx.x*2 + r)*NC + c] = a;
    }
}

extern "C" void kernel_launch(void* const* d_in, const int* in_sizes, int n_in,
                              void* d_out, int out_size, void* d_ws, size_t ws_size,
                              hipStream_t stream) {
    const float* time_features = (const float*)d_in[0];
    const float* tw            = (const float*)d_in[2];
    const float* freq_features = (const float*)d_in[3];
    const float* fw            = (const float*)d_in[4];
    const int*   labels        = (const int*)d_in[5];
    const int*   qsize         = (const int*)d_in[7];
    const float* Wt  = (const float*)d_in[8];
    const float* bt  = (const float*)d_in[9];
    const float* Wf  = (const float*)d_in[10];
    const float* bfv = (const float*)d_in[11];
    const float* Wc  = (const float*)d_in[12];
    const float* bc  = (const float*)d_in[13];
    const float* Wo  = (const float*)d_in[14];
    const float* bo  = (const float*)d_in[15];
    float* out = (float*)d_out;

    float* ws    = (float*)d_ws;
    float* Zt    = ws;                         // N*ET
    float* Zf    = Zt + (size_t)N*ET;          // N*ET
    float* Zc    = Zf + (size_t)N*ET;          // N*EC
    float* degT  = Zc + (size_t)N*EC;          // N   (zeroed)
    float* degF  = degT + N;                   // N   (zeroed)
    float* dsum  = degF + N;                   // N   (zeroed)
    float* colsb = dsum + N;                   // 8
    float* feats = colsb + 8;                  // N*FS
    float* Aw    = feats + (size_t)N*FS;       // N*N
    float* Pt    = Aw + (size_t)N*N;           // KC_ET*N*ET
    float* Pf    = Pt + (size_t)KC_ET*N*ET;    // KC_ET*N*ET
    float* Pe    = Pf + (size_t)KC_ET*N*ET;    // KC_EC*N*EC

    hipMemsetAsync(degT, 0, 3*N*sizeof(float), stream);
    k_deg_label<<<513, 256, 0, stream>>>(tw, fw, labels, degT, degF, colsb);
    k_xw2<<<dim3(N/8, 2), 256, 0, stream>>>(time_features, Wt, degT, Zt,
                                            freq_features, Wf, degF, Zf);
    k_agg_et<<<dim3(N/64, KC_ET), 256, 0, stream>>>(tw, fw, Zt, Zf, Pt, Pf);
    k_feats_epi<<<(N*64)/256, 256, 0, stream>>>(Pt, Pf, Zt, Zf, degT, degF,
                                                bt, bfv, colsb, qsize, feats);
    k_build_aw<<<dim3(N/64, N/64), 256, 0, stream>>>(feats, Aw, dsum);
    k_featswc<<<N/8, 256, 0, stream>>>(feats, Wc, dsum, Zc);
    k_agg_ec<<<dim3(N/128, KC_EC), 256, 0, stream>>>(Aw, Zc, Pe);
    k_embfinal<<<N/2, 256, 0, stream>>>(Pe, dsum, bc, Wo, bo, out);
}